// Round 2
// baseline (126.831 us; speedup 1.0000x reference)
//
#include <hip/hip_runtime.h>
#include <math.h>

// Problem constants (fixed by the reference):
#define NROWS 65536   // B*H*Wd = 8*64*128
#define DD    272     // capsule feature dim
#define NC    19      // num classes
#define NP    524288  // total points
#define NSEG  4096    // total instances
#define PS    20      // padded proj row stride (16B-aligned float4 rows)

#define PROJ_BLOCKS 1024   // 64 rows per block

// ---------------------------------------------------------------------------
// Kernel A (v3): projection GEMM + segment-boundary extraction, one grid.
//   - 1024 blocks x 256 threads; 64 rows/block; wave q handles d % 4 == q.
//   - 32-float chunks (2 float4/thread/phase): 9 phases (was 17). Rationale:
//     hipcc drains vmcnt(0) at EVERY __syncthreads, so register prefetch does
//     not survive barriers; the lever is fewer drains with more bytes in
//     flight at each (32 KB/CU >= BW*latency ~22 KB).
//   - boundary extraction folded into these same blocks (2 points/thread),
//     issued while the first X loads are in flight -> no trailing 2048-block
//     tail after the GEMM blocks retire.
//   - Xs double-buffer and R reduction buffer share one LDS allocation
//     (19.5 KB) since their live ranges are disjoint.
// ---------------------------------------------------------------------------
__global__ __launch_bounds__(256) void proj_bounds_kernel(
    const float* __restrict__ X, const float* __restrict__ W,
    const int* __restrict__ seg, float* __restrict__ proj,
    int* __restrict__ bnd) {
  const int t    = threadIdx.x;
  const int lane = t & 63;
  const int q    = __builtin_amdgcn_readfirstlane(t >> 6);  // wave-uniform
  const int row0 = blockIdx.x * 64;

  // LDS: Xs needs 2*64*33 = 4224 floats; R needs 4*64*19 = 4864 floats.
  // Disjoint live ranges -> one 4864-float allocation (19456 B -> 8 blk/CU).
  __shared__ float smem[4 * 64 * NC];
  float* Xs0 = smem;                 // buffer A: 64 rows x 32, pad stride 33
  float* Xs1 = smem + 64 * 33;      // buffer B
  float* R   = smem;                 // reduction view (after Xs is dead)

  const int r_ld = t >> 2;           // staging row (4 threads/row)
  const int c4   = t & 3;            // float4 slot within 16-float half
  const float* gsrc = X + (size_t)(row0 + r_ld) * DD + c4 * 4;
  float* dstA = &Xs0[r_ld * 33 + c4 * 4];
  float* dstB = &Xs1[r_ld * 33 + c4 * 4];

  // ---- issue chunk0 + chunk1 loads (4 float4 in flight) ----
  float4 a_lo = *(const float4*)(gsrc + 0);
  float4 a_hi = *(const float4*)(gsrc + 16);
  float4 b_lo = *(const float4*)(gsrc + 32);
  float4 b_hi = *(const float4*)(gsrc + 48);

  // ---- boundary extraction: 2 points/thread, overlaps the loads above ----
  {
    const int p0 = blockIdx.x * 512 + t * 2;
    int prev = (p0 == 0) ? -1 : seg[p0 - 1];
#pragma unroll
    for (int j = 0; j < 2; ++j) {
      const int p   = p0 + j;
      const int cur = seg[p];
      for (int s = prev + 1; s <= cur; ++s) bnd[s] = p;  // total <= NSEG+1
      if (p == NP - 1) {
        for (int s = cur + 1; s <= NSEG; ++s) bnd[s] = NP;
      }
      prev = cur;
    }
  }

  float acc[NC];
#pragma unroll
  for (int c = 0; c < NC; ++c) acc[c] = 0.f;

  // chunk ch covers d in [32ch, 32ch+32) for ch<8; chunk 8 covers [256,272).
#define STORE_LO(D, V) do { (D)[0]=(V).x; (D)[1]=(V).y; (D)[2]=(V).z; (D)[3]=(V).w; } while (0)
#define STORE_HI(D, V) do { (D)[16]=(V).x; (D)[17]=(V).y; (D)[18]=(V).z; (D)[19]=(V).w; } while (0)

#define COMPUTE(CH, XROW, NK) do {                                   \
    const float* xrow_ = (XROW) + lane * 33;                         \
    _Pragma("unroll")                                                \
    for (int k = 0; k < (NK); ++k) {                                 \
      const int c16_ = q + 4 * k;                                    \
      const float x_ = xrow_[c16_];     /* stride 33: 2-way, free */ \
      const float* wr_ = W + ((CH) * 32 + c16_) * NC; /* s_load */   \
      _Pragma("unroll")                                              \
      for (int c = 0; c < NC; ++c) acc[c] = fmaf(x_, wr_[c], acc[c]); \
    }                                                                \
  } while (0)

  // prologue: stage chunk0 -> A, prefetch chunk2
  STORE_LO(dstA, a_lo); STORE_HI(dstA, a_hi);
  a_lo = *(const float4*)(gsrc + 64);
  a_hi = *(const float4*)(gsrc + 80);
  __syncthreads();                        // chunk0 visible

  // steady state. invariants at top of iter i (c0 = 2i):
  //   A holds chunk c0; b regs hold chunk c0+1; a regs hold chunk c0+2.
#pragma unroll
  for (int i = 0; i < 3; ++i) {
    const int c0 = 2 * i;
    STORE_LO(dstB, b_lo); STORE_HI(dstB, b_hi);       // stage c0+1
    b_lo = *(const float4*)(gsrc + (c0 + 3) * 32);    // c0+3 in {3,5,7}
    b_hi = *(const float4*)(gsrc + (c0 + 3) * 32 + 16);
    COMPUTE(c0, Xs0, 8);
    __syncthreads();
    STORE_LO(dstA, a_lo); STORE_HI(dstA, a_hi);       // stage c0+2
    a_lo = *(const float4*)(gsrc + (c0 + 4) * 32);    // c0+4 in {4,6,8}
    if (c0 + 4 < 8)                                   // chunk 8 has lo half only
      a_hi = *(const float4*)(gsrc + (c0 + 4) * 32 + 16);
    COMPUTE(c0 + 1, Xs1, 8);
    __syncthreads();
  }

  // epilogue: A holds chunk6; b regs chunk7; a_lo chunk8 (16 floats).
  STORE_LO(dstB, b_lo); STORE_HI(dstB, b_hi);         // stage chunk7
  COMPUTE(6, Xs0, 8);
  __syncthreads();
  STORE_LO(dstA, a_lo);                               // stage chunk8 (lo only)
  COMPUTE(7, Xs1, 8);
  __syncthreads();
  COMPUTE(8, Xs0, 4);                                 // d = 256..271
  __syncthreads();                                    // Xs dead; R may reuse LDS

#undef COMPUTE
#undef STORE_LO
#undef STORE_HI

  // cross-wave reduction of the 4 d-residue partials
#pragma unroll
  for (int c = 0; c < NC; ++c) R[(q * 64 + lane) * NC + c] = acc[c];
  __syncthreads();
#pragma unroll
  for (int j = 0; j < 5; ++j) {
    int f = t + 256 * j;               // 0..1279 covers 64 rows x 20 cols
    int r = f / PS;
    int c = f % PS;
    float s = 0.f;
    if (c < NC) {
      s = R[r * NC + c] + R[(64 + r) * NC + c] +
          R[(128 + r) * NC + c] + R[(192 + r) * NC + c];
    }
    proj[(size_t)row0 * PS + f] = s;   // contiguous coalesced store (pad = 0)
  }
}

// ---------------------------------------------------------------------------
// Kernel B: per-segment mean of gathered proj rows + bias + sigmoid.
// 4 segments per 256-thread block (one per wave) -> up to 32 waves/CU;
// software-pipelined point_idx prefetch to break the idx->gather chain.
// ---------------------------------------------------------------------------
__global__ __launch_bounds__(256, 8) void pool_kernel(
    const float* __restrict__ proj, const int* __restrict__ point_idx,
    const int* __restrict__ bnd, const float* __restrict__ bias,
    float* __restrict__ out) {
  const int wave = threadIdx.x >> 6;
  const int lane = threadIdx.x & 63;
  const int s    = blockIdx.x * 4 + wave;
  const int start = bnd[s];
  const int end   = bnd[s + 1];

  float a[PS];
#pragma unroll
  for (int j = 0; j < PS; ++j) a[j] = 0.f;

  int p  = start + lane;
  int pi = (p < end) ? point_idx[p] : 0;
  while (p < end) {
    const int pn      = p + 64;
    const int pi_next = (pn < end) ? point_idx[pn] : 0;  // prefetch next idx
    const float4* row = (const float4*)(proj + (size_t)pi * PS);  // 80B aligned
    float4 r0 = row[0], r1 = row[1], r2 = row[2], r3 = row[3], r4 = row[4];
    a[0]  += r0.x; a[1]  += r0.y; a[2]  += r0.z; a[3]  += r0.w;
    a[4]  += r1.x; a[5]  += r1.y; a[6]  += r1.z; a[7]  += r1.w;
    a[8]  += r2.x; a[9]  += r2.y; a[10] += r2.z; a[11] += r2.w;
    a[12] += r3.x; a[13] += r3.y; a[14] += r3.z; a[15] += r3.w;
    a[16] += r4.x; a[17] += r4.y; a[18] += r4.z; a[19] += r4.w;
    pi = pi_next;
    p  = pn;
  }

  // butterfly reduce the 19 live accumulators across 64 lanes
#pragma unroll
  for (int off = 32; off > 0; off >>= 1) {
#pragma unroll
    for (int j = 0; j < NC; ++j) a[j] += __shfl_xor(a[j], off);
  }

  if (lane == 0) {
    const float inv = 1.f / fmaxf((float)(end - start), 1.f);
#pragma unroll
    for (int c = 0; c < NC; ++c) {
      float m = a[c] * inv + bias[c];
      out[s * NC + c] = 1.f / (1.f + expf(-m));
    }
  }
}

// ---------------------------------------------------------------------------
// Fallback (only if workspace is too small): direct full-D gather per segment.
// ---------------------------------------------------------------------------
__global__ __launch_bounds__(256) void fallback_kernel(
    const float* __restrict__ X, const float* __restrict__ W,
    const float* __restrict__ bias, const int* __restrict__ point_idx,
    const int* __restrict__ seg, float* __restrict__ out) {
  const int s = blockIdx.x;
  const int t = threadIdx.x;
  __shared__ float Ps[DD];

  int lo = 0, hi = NP;
  while (lo < hi) { int mid = (lo + hi) >> 1; if (seg[mid] <  s) lo = mid + 1; else hi = mid; }
  const int start = lo;
  hi = NP;
  while (lo < hi) { int mid = (lo + hi) >> 1; if (seg[mid] <= s) lo = mid + 1; else hi = mid; }
  const int end = lo;

  float a0 = 0.f, a1 = 0.f;
  for (int p = start; p < end; ++p) {
    const int pi = point_idx[p];
    const float* row = X + (size_t)pi * DD;
    a0 += row[t];
    if (t < DD - 256) a1 += row[256 + t];
  }
  const float inv = 1.f / fmaxf((float)(end - start), 1.f);
  Ps[t] = a0 * inv;
  if (t < DD - 256) Ps[256 + t] = a1 * inv;
  __syncthreads();

  if (t < NC) {
    float acc = bias[t];
    for (int d = 0; d < DD; ++d) acc = fmaf(Ps[d], W[d * NC + t], acc);
    out[s * NC + t] = 1.f / (1.f + expf(-acc));
  }
}

extern "C" void kernel_launch(void* const* d_in, const int* in_sizes, int n_in,
                              void* d_out, int out_size, void* d_ws, size_t ws_size,
                              hipStream_t stream) {
  const float* X         = (const float*)d_in[0];  // [65536, 272]
  const float* W         = (const float*)d_in[1];  // [272, 19]
  const float* bias      = (const float*)d_in[2];  // [19]
  const int*   point_idx = (const int*)d_in[3];    // [P]
  const int*   seg       = (const int*)d_in[4];    // [P] sorted
  float*       out       = (float*)d_out;          // [4096, 19]

  const size_t proj_bytes = (size_t)NROWS * PS * sizeof(float);     // 5.24 MB
  const size_t need = proj_bytes + (size_t)(NSEG + 1) * sizeof(int);
  if (ws_size >= need) {
    float* proj = (float*)d_ws;
    int*   bnd  = (int*)((char*)d_ws + proj_bytes);
    proj_bounds_kernel<<<PROJ_BLOCKS, 256, 0, stream>>>(X, W, seg, proj, bnd);
    pool_kernel<<<NSEG / 4, 256, 0, stream>>>(proj, point_idx, bnd, bias, out);
  } else {
    fallback_kernel<<<NSEG, 256, 0, stream>>>(X, W, bias, point_idx, seg, out);
  }
}